// Round 5
// baseline (154.503 us; speedup 1.0000x reference)
//
#include <hip/hip_runtime.h>
#include <hip/hip_bf16.h>

#define CC 64
#define HH 128
#define WW 128
#define HW (HH * WW)

typedef __attribute__((ext_vector_type(8))) short short8;
typedef __attribute__((ext_vector_type(4))) float floatx4;

// pack 8 fp32 (two float4) -> 8 bf16 (RTNE) in a short8
__device__ __forceinline__ short8 pack8(float4 a, float4 b) {
    __hip_bfloat162 p0 = __float22bfloat162_rn(make_float2(a.x, a.y));
    __hip_bfloat162 p1 = __float22bfloat162_rn(make_float2(a.z, a.w));
    __hip_bfloat162 p2 = __float22bfloat162_rn(make_float2(b.x, b.y));
    __hip_bfloat162 p3 = __float22bfloat162_rn(make_float2(b.z, b.w));
    unsigned u0, u1, u2, u3;
    __builtin_memcpy(&u0, &p0, 4); __builtin_memcpy(&u1, &p1, 4);
    __builtin_memcpy(&u2, &p2, 4); __builtin_memcpy(&u3, &p3, 4);
    short8 v;
    v[0] = (short)(u0 & 0xffffu); v[1] = (short)(u0 >> 16);
    v[2] = (short)(u1 & 0xffffu); v[3] = (short)(u1 >> 16);
    v[4] = (short)(u2 & 0xffffu); v[5] = (short)(u2 >> 16);
    v[6] = (short)(u3 & 0xffffu); v[7] = (short)(u3 >> 16);
    return v;
}

// Single fused kernel: on-the-fly W bf16 convert (permuted rows o=(c*9+t)),
// filter-gen GEMM via MFMA (bias as C-init), relu, register-direct 3x3
// dynamic combine in MFMA C-layout, then ONE per-wave LDS transpose so all
// output stores are 256B-contiguous. No barriers anywhere (per-wave LDS
// slices + within-wave in-order DS).
__global__ __launch_bounds__(256, 4) void ACDA_main_kernel(
    const float* __restrict__ x, const float* __restrict__ Wg,
    const float* __restrict__ bg, float* __restrict__ out)
{
    __shared__ float T[4][16][68];   // per-wave transpose slice; 2-way max alias

    const int tid  = threadIdx.x;
    const int wv   = tid >> 6;       // wave id == 16-channel group
    const int lane = tid & 63;
    const int quad = lane >> 4;
    const int l16  = lane & 15;

    const int bid = blockIdx.x;      // 2048 blocks = 8/CU, zero tail
    const int b   = bid & 7;         // batch == XCD slot (L2 locality)
    const int j   = bid >> 3;
    const int seg = j & 1;
    const int h   = (j >> 1) & 127;
    const int w0  = seg << 6;

    const float* __restrict__ xb = x + (size_t)b * CC * HW;

    // ---- B fragments (X tile, bf16) held in registers for all 9 chunks ----
    // B[k][n]: n = lane&15 (pixel), k = quad*8 + j (channel)
    short8 bfrag[4][2];
#pragma unroll
    for (int nt = 0; nt < 4; ++nt) {
#pragma unroll
        for (int ks = 0; ks < 2; ++ks) {
            short8 v;
            const unsigned w = (unsigned)(w0 + nt * 16 + l16);
#pragma unroll
            for (int jj = 0; jj < 8; jj += 2) {
                const unsigned c = (unsigned)(ks * 32 + quad * 8 + jj);
                float f0 = xb[(c * HH + h) * WW + w];
                float f1 = xb[((c + 1) * HH + h) * WW + w];
                __hip_bfloat162 p = __float22bfloat162_rn(make_float2(f0, f1));
                unsigned u;
                __builtin_memcpy(&u, &p, 4);
                v[jj]     = (short)(u & 0xffffu);
                v[jj + 1] = (short)(u >> 16);
            }
            bfrag[nt][ks] = v;
        }
    }

    // ---- clamped per-lane column offsets (element index), per (dj, nt) ----
    unsigned colofs[3][4];
#pragma unroll
    for (int dj = 0; dj < 3; ++dj)
#pragma unroll
        for (int nt = 0; nt < 4; ++nt) {
            int col = w0 + nt * 16 + l16 + dj - 1;
            col = col < 0 ? 0 : (col > 127 ? 127 : col);
            colofs[dj][nt] = (unsigned)col;
        }
    const bool badL = (w0 == 0)  && (l16 == 0);    // only OOB-left lane
    const bool badR = (w0 == 64) && (l16 == 15);   // only OOB-right lane

    // channel base offsets (element index into xb), lane-varying by quad
    unsigned cbase[4];
#pragma unroll
    for (int reg = 0; reg < 4; ++reg)
        cbase[reg] = (unsigned)((wv * 16 + quad * 4 + reg) * HW);

    float oacc[4][4];   // [nt][reg]
#pragma unroll
    for (int nt = 0; nt < 4; ++nt)
#pragma unroll
        for (int reg = 0; reg < 4; ++reg) oacc[nt][reg] = 0.f;

    // ---- 9 chunks: chunk t = kk tap t for all 16 channels of this wave ----
#pragma unroll
    for (int t = 0; t < 9; ++t) {
        const int di  = t / 3;
        const int dj  = t - 3 * di;
        const int row = h + di - 1;
        if (row >= 0 && row < HH) {          // wave-uniform skip at h edges
            // A[m][k]: m = l16 -> filter row (wv*16+m)*9+t, read fp32 direct
            const float* wr = Wg + (((wv * 16 + l16) * 9 + t) * 64 + quad * 8);
            float4 wa = *(const float4*)(wr);
            float4 wb_ = *(const float4*)(wr + 4);
            float4 wc = *(const float4*)(wr + 32);
            float4 wd = *(const float4*)(wr + 36);
            short8 a0 = pack8(wa, wb_);
            short8 a1 = pack8(wc, wd);
            // bias as MFMA C initializer: C-row (quad*4+reg) -> channel bias
            floatx4 bq;
#pragma unroll
            for (int reg = 0; reg < 4; ++reg)
                bq[reg] = bg[(wv * 16 + quad * 4 + reg) * 9 + t];
            floatx4 acc[4];
#pragma unroll
            for (int nt = 0; nt < 4; ++nt) {
                floatx4 z = bq;
                z = __builtin_amdgcn_mfma_f32_16x16x32_bf16(a0, bfrag[nt][0], z, 0, 0, 0);
                z = __builtin_amdgcn_mfma_f32_16x16x32_bf16(a1, bfrag[nt][1], z, 0, 0, 0);
                acc[nt] = z;
            }
            const unsigned rp = (unsigned)(row * WW);
#pragma unroll
            for (int nt = 0; nt < 4; ++nt)
#pragma unroll
                for (int reg = 0; reg < 4; ++reg) {
                    unsigned idx = cbase[reg] + rp + colofs[dj][nt];
                    float pv = xb[idx];
                    if (dj == 0 && nt == 0) pv = badL ? 0.f : pv;
                    if (dj == 2 && nt == 3) pv = badR ? 0.f : pv;
                    float fv = fmaxf(acc[nt][reg], 0.f);
                    oacc[nt][reg] = fmaf(fv, pv, oacc[nt][reg]);
                }
        }
    }

    // ---- ONE per-wave LDS transpose: C-layout -> lane=pixel, then 256B stores
#pragma unroll
    for (int nt = 0; nt < 4; ++nt)
#pragma unroll
        for (int reg = 0; reg < 4; ++reg)
            T[wv][quad * 4 + reg][nt * 16 + l16] = oacc[nt][reg];
    // no barrier: per-wave slice, within-wave in-order DS guarantees RAW

    float* ob = out + (size_t)b * CC * HW + h * WW + w0 + lane;
#pragma unroll
    for (int i = 0; i < 16; ++i)
        ob[(wv * 16 + i) * HW] = T[wv][i][lane];
}

extern "C" void kernel_launch(void* const* d_in, const int* in_sizes, int n_in,
                              void* d_out, int out_size, void* d_ws, size_t ws_size,
                              hipStream_t stream) {
    const float* x  = (const float*)d_in[0];
    const float* Wg = (const float*)d_in[1];
    const float* bg = (const float*)d_in[2];
    float* out = (float*)d_out;

    ACDA_main_kernel<<<dim3(8 * 128 * 2), dim3(256), 0, stream>>>(x, Wg, bg, out);
}